// Round 3
// baseline (11607.919 us; speedup 1.0000x reference)
//
#include <hip/hip_runtime.h>
#include <cstdint>
#include <cstddef>

typedef __bf16 bf16_t;
typedef __bf16 bf16x8 __attribute__((ext_vector_type(8)));
typedef __bf16 bf16x4 __attribute__((ext_vector_type(4)));
typedef float f32x4 __attribute__((ext_vector_type(4)));

#define N_TIN 336
#define N_TOUT 96
#define N_B   2048
#define N_D   64
#define N_H   512
#define NBLK  256

__device__ __forceinline__ float sigmf(float x) { return 1.0f / (1.0f + __expf(-x)); }
__device__ __forceinline__ float tanhft(float x) {
  x = fminf(15.0f, fmaxf(-15.0f, x));
  float e = __expf(2.0f * x);
  return (e - 1.0f) / (e + 1.0f);
}

// ---------------- prep: W_eff = dWhh + dWih @ linW (raw [4H][512] bf16) ----------------
__global__ void prep_weff(const float* __restrict__ dWih, const float* __restrict__ dWhh,
                          const float* __restrict__ linW, bf16_t* __restrict__ Weff) {
  int n = blockIdx.x;
  for (int k = threadIdx.x; k < N_H; k += 256) {
    float acc = dWhh[(size_t)n * N_H + k];
    #pragma unroll 8
    for (int d = 0; d < 64; ++d) acc += dWih[(size_t)n * 64 + d] * linW[(size_t)d * N_H + k];
    Weff[(size_t)n * N_H + k] = (bf16_t)acc;
  }
}

__global__ void cvt_bf16_v4(const float* __restrict__ src, bf16_t* __restrict__ dst, int n4) {
  int i = blockIdx.x * 256 + threadIdx.x;
  int stride = gridDim.x * 256;
  for (; i < n4; i += stride) {
    float4 v = ((const float4*)src)[i];
    bf16x4 o;
    o[0] = (bf16_t)v.x; o[1] = (bf16_t)v.y; o[2] = (bf16_t)v.z; o[3] = (bf16_t)v.w;
    *(bf16x4*)(dst + (size_t)i * 4) = o;
  }
}

// ---------------- persistent seq2seq kernel (NO cooperative launch) ----------------
// 256 WGs (1/CU, 128 KiB LDS) x 512 threads. WG tile: 128 rows x 128 gate cols.
// Gate-interleaved col permutation: LDS col c -> weight row n = ((c>>4)&3)*512 +
// (cb*2+(c>>6))*16 + (c&15), so one 64-col wave slice = {i,f,g,o} of 16 h-units and
// all 4 gates of unit jn land in ONE lane's accumulators. c state fully in registers.
// LDS holds only the K=512 h-part of W: [kc=16][k8=4][col=128][8 bf16] = 128 KiB.
// Encoder x-part (K=64) B-fragments live in 32 VGPRs, loaded once.
__global__ __launch_bounds__(512, 1)
void lstm_persist(const bf16_t* __restrict__ xb,
                  const float* __restrict__ eWih, const float* __restrict__ eWhh,
                  const float* __restrict__ ebih, const float* __restrict__ ebhh,
                  const float* __restrict__ dWih, const float* __restrict__ dWhh,
                  const float* __restrict__ dbih, const float* __restrict__ dbhh,
                  const float* __restrict__ linb, const bf16_t* __restrict__ Weff,
                  const bf16_t* __restrict__ linWb,
                  bf16_t* __restrict__ hb0, bf16_t* __restrict__ hb1,
                  float* __restrict__ out, unsigned* bar)
{
  __shared__ __align__(16) char smem[16 * 8192];   // 131072 B exactly
  const int tid  = threadIdx.x;
  const int lane = tid & 63;
  const int w    = tid >> 6;
  const int wr   = w >> 1, wc = w & 1;
  const int rb   = (int)blockIdx.x >> 4, cb = (int)blockIdx.x & 15;
  const int fr   = lane & 15, hi = lane >> 4;
  const int jn   = (cb * 2 + wc) * 16 + fr;        // h-unit col owned by this lane

  // ---- software grid barrier (monotonic counter, agent scope) ----
  unsigned barcnt = 0;
  bool broken = false;
  auto gbar = [&]() {
    __syncthreads();
    if (tid == 0) {
      barcnt += NBLK;
      if (!broken) {
        __hip_atomic_fetch_add(bar, 1u, __ATOMIC_ACQ_REL, __HIP_MEMORY_SCOPE_AGENT);
        unsigned guard = 0;
        while (__hip_atomic_load(bar, __ATOMIC_ACQUIRE, __HIP_MEMORY_SCOPE_AGENT) < barcnt) {
          if (++guard > (1u << 24)) { broken = true; break; }   // escape: no hang
          __builtin_amdgcn_s_sleep(2);
        }
      }
    }
    __syncthreads();
  };

  // ---- LDS stagers (h-part K=512 only) ----
  auto stage_f32 = [&](const float* Wsrc) {        // Wsrc[n*512 + k]
    for (int s = tid; s < 16 * 4 * 128; s += 512) {
      int kc = s >> 9, k8 = (s >> 7) & 3, c = s & 127;
      int n  = ((c >> 4) & 3) * N_H + (cb * 2 + (c >> 6)) * 16 + (c & 15);
      const float* src = Wsrc + (size_t)n * N_H + kc * 32 + k8 * 8;
      bf16x8 o;
      #pragma unroll
      for (int e = 0; e < 8; ++e) o[e] = (bf16_t)src[e];
      *(bf16x8*)(smem + (size_t)s * 16) = o;
    }
  };
  auto stage_bf16 = [&](const bf16_t* Wsrc) {
    for (int s = tid; s < 16 * 4 * 128; s += 512) {
      int kc = s >> 9, k8 = (s >> 7) & 3, c = s & 127;
      int n  = ((c >> 4) & 3) * N_H + (cb * 2 + (c >> 6)) * 16 + (c & 15);
      *(bf16x8*)(smem + (size_t)s * 16) =
          *(const bf16x8*)(Wsrc + (size_t)n * N_H + kc * 32 + k8 * 8);
    }
  };

  // ---- encoder weights: h-part -> LDS, x-part -> registers ----
  stage_f32(eWhh);
  bf16x8 bvx[2][4];
  #pragma unroll
  for (int kc = 0; kc < 2; ++kc)
    #pragma unroll
    for (int ci = 0; ci < 4; ++ci) {
      const float* src = eWih + (size_t)(ci * N_H + jn) * 64 + kc * 32 + hi * 8;
      bf16x8 o;
      #pragma unroll
      for (int e = 0; e < 8; ++e) o[e] = (bf16_t)src[e];
      bvx[kc][ci] = o;
    }
  float bg[4];
  #pragma unroll
  for (int ci = 0; ci < 4; ++ci) bg[ci] = ebih[ci * N_H + jn] + ebhh[ci * N_H + jn];
  __syncthreads();

  const int rowA = rb * 128 + wr * 32;
  const size_t aoff_x = (size_t)(rowA + fr) * N_D + hi * 8;
  const size_t aoff_h = (size_t)(rowA + fr) * N_H + hi * 8;
  const int bbase = hi * 2048 + (wc * 64 + fr) * 16;

  float cc[8];
  #pragma unroll
  for (int i = 0; i < 8; ++i) cc[i] = 0.0f;

  auto gates_x = [&](const bf16_t* xp, f32x4 (&acc)[2][4]) {
    #pragma unroll
    for (int kc = 0; kc < 2; ++kc) {
      bf16x8 av0 = *(const bf16x8*)(xp + aoff_x + kc * 32);
      bf16x8 av1 = *(const bf16x8*)(xp + aoff_x + kc * 32 + 16 * N_D);
      #pragma unroll
      for (int ci = 0; ci < 4; ++ci) {
        acc[0][ci] = __builtin_amdgcn_mfma_f32_16x16x32_bf16(av0, bvx[kc][ci], acc[0][ci], 0, 0, 0);
        acc[1][ci] = __builtin_amdgcn_mfma_f32_16x16x32_bf16(av1, bvx[kc][ci], acc[1][ci], 0, 0, 0);
      }
    }
  };
  auto gates_h = [&](const bf16_t* hp, f32x4 (&acc)[2][4]) {
    const bf16_t* a0 = hp + aoff_h;
    #pragma unroll
    for (int kc = 0; kc < 16; ++kc) {
      bf16x8 av0 = *(const bf16x8*)(a0 + kc * 32);
      bf16x8 av1 = *(const bf16x8*)(a0 + kc * 32 + 16 * N_H);
      bf16x8 bv[4];
      #pragma unroll
      for (int ci = 0; ci < 4; ++ci)
        bv[ci] = *(const bf16x8*)(smem + kc * 8192 + bbase + ci * 256);
      #pragma unroll
      for (int ci = 0; ci < 4; ++ci) {
        acc[0][ci] = __builtin_amdgcn_mfma_f32_16x16x32_bf16(av0, bv[ci], acc[0][ci], 0, 0, 0);
        acc[1][ci] = __builtin_amdgcn_mfma_f32_16x16x32_bf16(av1, bv[ci], acc[1][ci], 0, 0, 0);
      }
    }
  };
  auto pwstore = [&](f32x4 (&acc)[2][4], bf16_t* hn) {
    #pragma unroll
    for (int ri = 0; ri < 2; ++ri) {
      #pragma unroll
      for (int r = 0; r < 4; ++r) {
        float gi = sigmf(acc[ri][0][r] + bg[0]);
        float gf = sigmf(acc[ri][1][r] + bg[1]);
        float gg = tanhft(acc[ri][2][r] + bg[2]);
        float go = sigmf(acc[ri][3][r] + bg[3]);
        float cn = gf * cc[ri * 4 + r] + gi * gg;
        cc[ri * 4 + r] = cn;
        int row = rowA + ri * 16 + hi * 4 + r;
        hn[(size_t)row * N_H + jn] = (bf16_t)(go * tanhft(cn));
      }
    }
  };

  const int gw    = (int)blockIdx.x * 8 + w;
  const bool ywave = (gw & 3) == 0;
  const int ytile  = gw >> 2;                      // 0..511
  const int ytr = ytile >> 2, ytc = ytile & 3;
  auto yproj = [&](int s, const bf16_t* hp) {
    f32x4 ya = {0.f, 0.f, 0.f, 0.f};
    const bf16_t* ha = hp    + (size_t)(ytr * 16 + fr) * N_H + hi * 8;
    const bf16_t* wa = linWb + (size_t)(ytc * 16 + fr) * N_H + hi * 8;
    #pragma unroll
    for (int kc = 0; kc < 16; ++kc)
      ya = __builtin_amdgcn_mfma_f32_16x16x32_bf16(*(const bf16x8*)(ha + kc * 32),
                                                   *(const bf16x8*)(wa + kc * 32), ya, 0, 0, 0);
    float lb = linb[ytc * 16 + fr];
    #pragma unroll
    for (int r = 0; r < 4; ++r) {
      int row = ytr * 16 + hi * 4 + r;
      out[(size_t)s * N_B * N_D + (size_t)row * N_D + ytc * 16 + fr] = ya[r] + lb;
    }
  };

  // ---- phase 0: h=0, c=0 -> x-part only ----
  {
    f32x4 acc[2][4] = {};
    gates_x(xb, acc);
    pwstore(acc, hb1);
  }
  gbar();

  // ---- encoder 1..335 ----
  for (int p = 1; p < N_TIN; ++p) {
    const bf16_t* hcur = (p & 1) ? hb1 : hb0;
    bf16_t*       hnxt = (p & 1) ? hb0 : hb1;
    f32x4 acc[2][4] = {};
    gates_x(xb + (size_t)p * N_B * N_D, acc);
    gates_h(hcur, acc);
    pwstore(acc, hnxt);
    gbar();
  }
  // final encoder h in hb0

  // ---- decoder step 0: x=0 -> W = dWhh only ----
  __syncthreads();
  stage_f32(dWhh);
  #pragma unroll
  for (int ci = 0; ci < 4; ++ci) bg[ci] = dbih[ci * N_H + jn] + dbhh[ci * N_H + jn];
  __syncthreads();
  {
    f32x4 acc[2][4] = {};
    gates_h(hb0, acc);
    pwstore(acc, hb1);
  }
  gbar();

  // ---- decoder 1..95: folded W_eff = dWhh + dWih@linW, b_eff = b + dWih@linb ----
  __syncthreads();
  stage_bf16(Weff);
  #pragma unroll
  for (int ci = 0; ci < 4; ++ci) {
    float a = bg[ci];
    const float* wr_ = dWih + (size_t)(ci * N_H + jn) * 64;
    #pragma unroll 8
    for (int d = 0; d < 64; ++d) a += wr_[d] * linb[d];
    bg[ci] = a;
  }
  __syncthreads();

  for (int p = N_TIN + 1; p < N_TIN + N_TOUT; ++p) {
    const bf16_t* hcur = (p & 1) ? hb1 : hb0;
    bf16_t*       hnxt = (p & 1) ? hb0 : hb1;
    if (ywave) yproj(p - N_TIN - 1, hcur);       // y for previous decoder h
    f32x4 acc[2][4] = {};
    gates_h(hcur, acc);
    pwstore(acc, hnxt);
    gbar();
  }
  if (ywave) yproj(N_TOUT - 1, hb0);             // h_dec95 ended in hb0
}

// ---------------- host ----------------
extern "C" void kernel_launch(void* const* d_in, const int* in_sizes, int n_in,
                              void* d_out, int out_size, void* d_ws, size_t ws_size,
                              hipStream_t stream) {
  (void)in_sizes; (void)n_in; (void)out_size; (void)ws_size;
  const float* x_f  = (const float*)d_in[0];
  const float* eWih = (const float*)d_in[1];
  const float* eWhh = (const float*)d_in[2];
  const float* ebih = (const float*)d_in[3];
  const float* ebhh = (const float*)d_in[4];
  const float* dWih = (const float*)d_in[5];
  const float* dWhh = (const float*)d_in[6];
  const float* dbih = (const float*)d_in[7];
  const float* dbhh = (const float*)d_in[8];
  const float* linW = (const float*)d_in[9];
  const float* linb = (const float*)d_in[10];
  float* out = (float*)d_out;

  char* ws = (char*)d_ws;
  size_t off = 0;
  auto alloc = [&](size_t bytes) {
    char* p = ws + off;
    off += (bytes + 255) & ~(size_t)255;
    return p;
  };
  bf16_t*  Weff  = (bf16_t*)alloc(2048ull * 512 * 2);
  bf16_t*  linWb = (bf16_t*)alloc(64ull * 512 * 2);
  bf16_t*  xb    = (bf16_t*)alloc((size_t)N_TIN * N_B * N_D * 2);
  bf16_t*  hb0   = (bf16_t*)alloc((size_t)N_B * N_H * 2);
  bf16_t*  hb1   = (bf16_t*)alloc((size_t)N_B * N_H * 2);
  unsigned* bar  = (unsigned*)alloc(256);

  prep_weff<<<2048, 256, 0, stream>>>(dWih, dWhh, linW, Weff);
  cvt_bf16_v4<<<32, 256, 0, stream>>>(linW, linWb, 64 * 512 / 4);
  cvt_bf16_v4<<<2048, 256, 0, stream>>>(x_f, xb, N_TIN * N_B * N_D / 4);
  hipMemsetAsync(bar, 0, 256, stream);

  lstm_persist<<<dim3(256), dim3(512), 0, stream>>>(
      xb, eWih, eWhh, ebih, ebhh, dWih, dWhh, dbih, dbhh,
      linb, Weff, linWb, hb0, hb1, out, bar);
}

// Round 4
// 5427.079 us; speedup vs baseline: 2.1389x; 2.1389x over previous
//
#include <hip/hip_runtime.h>
#include <cstdint>
#include <cstddef>

typedef __bf16 bf16_t;
typedef __bf16 bf16x8 __attribute__((ext_vector_type(8)));
typedef __bf16 bf16x4 __attribute__((ext_vector_type(4)));
typedef float f32x4 __attribute__((ext_vector_type(4)));

#define N_TIN 336
#define N_TOUT 96
#define N_B   2048
#define N_D   64
#define N_H   512
#define NBLK  256

__device__ __forceinline__ float sigmf(float x) { return 1.0f / (1.0f + __expf(-x)); }
__device__ __forceinline__ float tanhft(float x) {
  x = fminf(15.0f, fmaxf(-15.0f, x));
  float e = __expf(2.0f * x);
  return (e - 1.0f) / (e + 1.0f);
}
__device__ __forceinline__ unsigned short bfbits(float f) {
  bf16_t b = (bf16_t)f;
  return __builtin_bit_cast(unsigned short, b);
}

// ---- asm memory helpers: sc0 sc1 = coherent at Infinity Cache (bypass L1/L2) ----
__device__ __forceinline__ bf16x8 ld16_sc(const void* p) {
  bf16x8 r;
  asm volatile("global_load_dwordx4 %0, %1, off sc0 sc1" : "=v"(r) : "v"(p));
  return r;
}
__device__ __forceinline__ bf16x8 ld16_ca(const void* p) {
  bf16x8 r;
  asm volatile("global_load_dwordx4 %0, %1, off" : "=v"(r) : "v"(p));
  return r;
}
__device__ __forceinline__ void st2_sc(void* p, unsigned v) {
  asm volatile("global_store_short %0, %1, off sc0 sc1" :: "v"(p), "v"(v) : "memory");
}
__device__ __forceinline__ unsigned ld32_sc(const unsigned* p) {
  unsigned r;
  asm volatile("global_load_dword %0, %1, off sc0 sc1\n\ts_waitcnt vmcnt(0)"
               : "=v"(r) : "v"(p) : "memory");
  return r;
}
template<int N> __device__ __forceinline__ void wait_vm() {
  asm volatile("s_waitcnt vmcnt(%0)" :: "i"(N) : "memory");
  __builtin_amdgcn_sched_barrier(0);
}

// ---------------- prep kernels ----------------
__global__ void prep_weff(const float* __restrict__ dWih, const float* __restrict__ dWhh,
                          const float* __restrict__ linW, bf16_t* __restrict__ Weff) {
  int n = blockIdx.x;
  for (int k = threadIdx.x; k < N_H; k += 256) {
    float acc = dWhh[(size_t)n * N_H + k];
    #pragma unroll 8
    for (int d = 0; d < 64; ++d) acc += dWih[(size_t)n * 64 + d] * linW[(size_t)d * N_H + k];
    Weff[(size_t)n * N_H + k] = (bf16_t)acc;
  }
}

__global__ void cvt_bf16_v4(const float* __restrict__ src, bf16_t* __restrict__ dst, int n4) {
  int i = blockIdx.x * 256 + threadIdx.x;
  int stride = gridDim.x * 256;
  for (; i < n4; i += stride) {
    float4 v = ((const float4*)src)[i];
    bf16x4 o;
    o[0] = (bf16_t)v.x; o[1] = (bf16_t)v.y; o[2] = (bf16_t)v.z; o[3] = (bf16_t)v.w;
    *(bf16x4*)(dst + (size_t)i * 4) = o;
  }
}

// Wx[cb][kcx][ci][hi][fr][8e]: encoder x-weights, bf16, per-lane 16B frags
__global__ void prep_wx(const float* __restrict__ Wih, bf16_t* __restrict__ Wx) {
  int cb = blockIdx.x;
  for (int idx = threadIdx.x; idx < 8192; idx += 256) {
    int e = idx & 7, fr = (idx >> 3) & 15, hi = (idx >> 7) & 3, ci = (idx >> 9) & 7, kcx = idx >> 12;
    int c = ci * 16 + fr;
    int gate = (c >> 4) & 3;
    int unit = (cb * 2 + (c >> 6)) * 16 + (c & 15);
    int k = kcx * 32 + hi * 8 + e;
    Wx[(size_t)cb * 8192 + idx] = (bf16_t)Wih[(size_t)(gate * N_H + unit) * 64 + k];
  }
}

// ---------------- unrolled K-chains (compile-time vmcnt counts) ----------------
template<int KC>
__device__ __forceinline__ void h_chain(const char* sm, int bofs,
                                        const bf16x8 (&hv)[16], f32x4 (&acc)[8]) {
  bf16x8 bv[8];
  #pragma unroll
  for (int ci = 0; ci < 8; ++ci)
    bv[ci] = *(const bf16x8*)(sm + KC * 8192 + bofs + ci * 256);
  wait_vm<15 - KC>();
  #pragma unroll
  for (int ci = 0; ci < 8; ++ci)
    acc[ci] = __builtin_amdgcn_mfma_f32_16x16x32_bf16(hv[KC], bv[ci], acc[ci], 0, 0, 0);
  if constexpr (KC < 15) h_chain<KC + 1>(sm, bofs, hv, acc);
}
template<int KC>
__device__ __forceinline__ void y_chain(const bf16x8 (&hv)[16], const bf16x8 (&wv)[16],
                                        f32x4& ya) {
  wait_vm<15 - KC>();
  ya = __builtin_amdgcn_mfma_f32_16x16x32_bf16(hv[KC], wv[KC], ya, 0, 0, 0);
  if constexpr (KC < 15) y_chain<KC + 1>(hv, wv, ya);
}

// ---------------- persistent seq2seq kernel ----------------
// 256 WGs (1/CU) x 512 threads = 8 waves; wave w owns rows [rb*128+w*16, +16) x all
// 128 gate-cols of WG col-block cb. Gate-interleaved cols: lane (fr,hi) owns all 4
// gates of h-units jn(u2)=(cb*2+u2)*16+fr, u2=0,1 -> pointwise is register-local.
// W h-part in LDS (128 KiB, [kc16][k8=4][col128][8] conflict-free b128 reads).
// h exchanged via sc0/sc1 (Infinity-Cache-coherent); x/W stay L2-cached.
__global__ __launch_bounds__(512, 1)
void lstm_persist(const bf16_t* __restrict__ xb, const bf16_t* __restrict__ Wx,
                  const float* __restrict__ eWhh,
                  const float* __restrict__ ebih, const float* __restrict__ ebhh,
                  const float* __restrict__ dWih, const float* __restrict__ dWhh,
                  const float* __restrict__ dbih, const float* __restrict__ dbhh,
                  const float* __restrict__ linb, const bf16_t* __restrict__ Weff,
                  const bf16_t* __restrict__ linWb,
                  bf16_t* __restrict__ hb0, bf16_t* __restrict__ hb1,
                  float* __restrict__ out, unsigned* __restrict__ leafp)
{
  __shared__ __align__(16) char smem[16 * 8192];   // 131072 B
  __shared__ unsigned bro_s;
  const int tid  = threadIdx.x;
  const int lane = tid & 63;
  const int w    = tid >> 6;
  const int bid  = (int)blockIdx.x;
  const int rb   = bid >> 4, cb = bid & 15;
  const int fr   = lane & 15, hi = lane >> 4;
  const int rowW = rb * 128 + w * 16;
  const int jn0  = (cb * 2) * 16 + fr, jn1 = jn0 + 16;
  const size_t aoff_h = (size_t)(rowW + fr) * N_H + hi * 8;
  const size_t aoff_x = (size_t)(rowW + fr) * N_D + hi * 8;
  const int bofs = hi * 2048 + fr * 16;
  const char* wxl = (const char*)Wx + cb * 16384 + (hi * 16 + fr) * 16;

  if (tid == 0) bro_s = 0;

  // ---- LDS stagers for the K=512 h-part ----
  auto stage_f32 = [&](const float* Wsrc) {
    for (int s = tid; s < 16 * 4 * 128; s += 512) {
      int kc = s >> 9, k8 = (s >> 7) & 3, c = s & 127;
      int n  = ((c >> 4) & 3) * N_H + (cb * 2 + (c >> 6)) * 16 + (c & 15);
      const float* src = Wsrc + (size_t)n * N_H + kc * 32 + k8 * 8;
      bf16x8 o;
      #pragma unroll
      for (int e = 0; e < 8; ++e) o[e] = (bf16_t)src[e];
      *(bf16x8*)(smem + (size_t)s * 16) = o;
    }
  };
  auto stage_bf16 = [&](const bf16_t* Wsrc) {
    for (int s = tid; s < 16 * 4 * 128; s += 512) {
      int kc = s >> 9, k8 = (s >> 7) & 3, c = s & 127;
      int n  = ((c >> 4) & 3) * N_H + (cb * 2 + (c >> 6)) * 16 + (c & 15);
      *(bf16x8*)(smem + (size_t)s * 16) =
          *(const bf16x8*)(Wsrc + (size_t)n * N_H + kc * 32 + k8 * 8);
    }
  };

  // ---- encoder phase setup ----
  stage_f32(eWhh);
  float bg[4][2];
  #pragma unroll
  for (int g = 0; g < 4; ++g) {
    bg[g][0] = ebih[g * N_H + jn0] + ebhh[g * N_H + jn0];
    bg[g][1] = ebih[g * N_H + jn1] + ebhh[g * N_H + jn1];
  }
  __syncthreads();

  float cc[8];
  #pragma unroll
  for (int i = 0; i < 8; ++i) cc[i] = 0.0f;

  // ---- software grid barrier: vmcnt(0) + 8 leaf counters + 8-lane poll ----
  unsigned bstep = 0;
  auto gbar = [&]() {
    ++bstep;
    asm volatile("s_waitcnt vmcnt(0)" ::: "memory");
    __syncthreads();
    if (tid == 0) atomicAdd(leafp + ((bid & 7) << 5), 1u);
    if (w == 0) {
      const unsigned tgt = bstep * 32u;
      unsigned guard = 0;
      while (true) {
        unsigned v = tgt;
        if (lane < 8 && bro_s == 0) v = ld32_sc(leafp + (lane << 5));
        if (__all(v >= tgt)) break;
        if (++guard > (1u << 18)) { if (lane == 0) bro_s = 1u; }
        __builtin_amdgcn_s_sleep(2);
      }
    }
    __syncthreads();
  };

  auto pwstore = [&](f32x4 (&acc)[8], bf16_t* hn) {
    #pragma unroll
    for (int u2 = 0; u2 < 2; ++u2) {
      const int jn = u2 ? jn1 : jn0;
      #pragma unroll
      for (int r = 0; r < 4; ++r) {
        float gi = sigmf(acc[4 * u2 + 0][r] + bg[0][u2]);
        float gf = sigmf(acc[4 * u2 + 1][r] + bg[1][u2]);
        float gg = tanhft(acc[4 * u2 + 2][r] + bg[2][u2]);
        float go = sigmf(acc[4 * u2 + 3][r] + bg[3][u2]);
        float cn = gf * cc[u2 * 4 + r] + gi * gg;
        cc[u2 * 4 + r] = cn;
        st2_sc(hn + (size_t)(rowW + hi * 4 + r) * N_H + jn, (unsigned)bfbits(go * tanhft(cn)));
      }
    }
  };

  // ---- y projection (piggybacked on 1/4 of waves during decoder) ----
  const int gw = bid * 8 + w;
  const bool ywave = (gw & 3) == 0;
  const int ytile = gw >> 2;                 // 0..511
  const int ytr = ytile >> 2, ytc = ytile & 3;
  const float lb = linb[ytc * 16 + fr];
  auto yproj = [&](int s, const bf16_t* hp) {
    bf16x8 wv[16], hv2[16];
    const bf16_t* wa = linWb + (size_t)(ytc * 16 + fr) * N_H + hi * 8;
    const bf16_t* ha = hp + (size_t)(ytr * 16 + fr) * N_H + hi * 8;
    #pragma unroll
    for (int k = 0; k < 16; ++k) wv[k] = ld16_ca(wa + k * 32);
    #pragma unroll
    for (int k = 0; k < 16; ++k) hv2[k] = ld16_sc(ha + k * 32);
    wait_vm<16>();
    f32x4 ya = {0.f, 0.f, 0.f, 0.f};
    y_chain<0>(hv2, wv, ya);
    #pragma unroll
    for (int r = 0; r < 4; ++r)
      out[(size_t)s * (N_B * N_D) + (size_t)(ytr * 16 + hi * 4 + r) * N_D + ytc * 16 + fr]
          = ya[r] + lb;
    wait_vm<0>();                            // drain y stores before counted region
  };

  // ---- encoder step 0 (h=0, c=0: x-part only) ----
  {
    f32x4 acc[8] = {};
    bf16x8 xw0[8], xw1[8], xa0, xa1;
    #pragma unroll
    for (int i = 0; i < 8; ++i) xw0[i] = ld16_ca(wxl + i * 1024);
    xa0 = ld16_ca(xb + aoff_x);
    #pragma unroll
    for (int i = 0; i < 8; ++i) xw1[i] = ld16_ca(wxl + 8192 + i * 1024);
    xa1 = ld16_ca(xb + aoff_x + 32);
    wait_vm<0>();
    #pragma unroll
    for (int ci = 0; ci < 8; ++ci)
      acc[ci] = __builtin_amdgcn_mfma_f32_16x16x32_bf16(xa0, xw0[ci], acc[ci], 0, 0, 0);
    #pragma unroll
    for (int ci = 0; ci < 8; ++ci)
      acc[ci] = __builtin_amdgcn_mfma_f32_16x16x32_bf16(xa1, xw1[ci], acc[ci], 0, 0, 0);
    pwstore(acc, hb1);
  }
  gbar();

  // ---- encoder steps 1..335 ----
  for (int p = 1; p < N_TIN; ++p) {
    const bf16_t* hp = (p & 1) ? hb1 : hb0;
    bf16_t*       hn = (p & 1) ? hb0 : hb1;
    const bf16_t* xp = xb + (size_t)p * N_B * N_D;
    f32x4 acc[8] = {};
    bf16x8 xw0[8], xw1[8], xa0, xa1, hv[16];
    #pragma unroll
    for (int i = 0; i < 8; ++i) xw0[i] = ld16_ca(wxl + i * 1024);
    xa0 = ld16_ca(xp + aoff_x);
    #pragma unroll
    for (int i = 0; i < 8; ++i) xw1[i] = ld16_ca(wxl + 8192 + i * 1024);
    xa1 = ld16_ca(xp + aoff_x + 32);
    #pragma unroll
    for (int kc = 0; kc < 16; ++kc) hv[kc] = ld16_sc(hp + aoff_h + kc * 32);
    wait_vm<25>();                           // 34 issued; oldest 9 (xw0,xa0) done
    #pragma unroll
    for (int ci = 0; ci < 8; ++ci)
      acc[ci] = __builtin_amdgcn_mfma_f32_16x16x32_bf16(xa0, xw0[ci], acc[ci], 0, 0, 0);
    wait_vm<16>();                           // xw1,xa1 done; 16 h-loads in flight
    #pragma unroll
    for (int ci = 0; ci < 8; ++ci)
      acc[ci] = __builtin_amdgcn_mfma_f32_16x16x32_bf16(xa1, xw1[ci], acc[ci], 0, 0, 0);
    h_chain<0>(smem, bofs, hv, acc);
    pwstore(acc, hn);
    gbar();
  }
  // final encoder h in hb0

  // ---- decoder step 0: x=0 -> W = dWhh ----
  __syncthreads();
  stage_f32(dWhh);
  #pragma unroll
  for (int g = 0; g < 4; ++g) {
    bg[g][0] = dbih[g * N_H + jn0] + dbhh[g * N_H + jn0];
    bg[g][1] = dbih[g * N_H + jn1] + dbhh[g * N_H + jn1];
  }
  __syncthreads();
  {
    f32x4 acc[8] = {};
    bf16x8 hv[16];
    #pragma unroll
    for (int kc = 0; kc < 16; ++kc) hv[kc] = ld16_sc(hb0 + aoff_h + kc * 32);
    h_chain<0>(smem, bofs, hv, acc);
    pwstore(acc, hb1);
  }
  gbar();

  // ---- decoder 1..95: folded W_eff = dWhh + dWih@linW, b_eff = b + dWih@linb ----
  __syncthreads();
  stage_bf16(Weff);
  #pragma unroll
  for (int g = 0; g < 4; ++g) {
    #pragma unroll
    for (int u2 = 0; u2 < 2; ++u2) {
      const float* wr_ = dWih + (size_t)(g * N_H + (u2 ? jn1 : jn0)) * 64;
      float a = bg[g][u2];
      #pragma unroll 8
      for (int d = 0; d < 64; ++d) a += wr_[d] * linb[d];
      bg[g][u2] = a;
    }
  }
  __syncthreads();

  for (int p = N_TIN + 1; p < N_TIN + N_TOUT; ++p) {
    const bf16_t* hp = (p & 1) ? hb1 : hb0;
    bf16_t*       hn = (p & 1) ? hb0 : hb1;
    if (ywave) yproj(p - N_TIN - 1, hp);     // y of previous decoder h
    f32x4 acc[8] = {};
    bf16x8 hv[16];
    #pragma unroll
    for (int kc = 0; kc < 16; ++kc) hv[kc] = ld16_sc(hp + aoff_h + kc * 32);
    h_chain<0>(smem, bofs, hv, acc);
    pwstore(acc, hn);
    gbar();
  }
  if (ywave) yproj(N_TOUT - 1, hb0);         // h_dec95 ended in hb0
}

// ---------------- host ----------------
extern "C" void kernel_launch(void* const* d_in, const int* in_sizes, int n_in,
                              void* d_out, int out_size, void* d_ws, size_t ws_size,
                              hipStream_t stream) {
  (void)in_sizes; (void)n_in; (void)out_size; (void)ws_size;
  const float* x_f  = (const float*)d_in[0];
  const float* eWih = (const float*)d_in[1];
  const float* eWhh = (const float*)d_in[2];
  const float* ebih = (const float*)d_in[3];
  const float* ebhh = (const float*)d_in[4];
  const float* dWih = (const float*)d_in[5];
  const float* dWhh = (const float*)d_in[6];
  const float* dbih = (const float*)d_in[7];
  const float* dbhh = (const float*)d_in[8];
  const float* linW = (const float*)d_in[9];
  const float* linb = (const float*)d_in[10];
  float* out = (float*)d_out;

  char* ws = (char*)d_ws;
  size_t off = 0;
  auto alloc = [&](size_t bytes) {
    char* p = ws + off;
    off += (bytes + 255) & ~(size_t)255;
    return p;
  };
  bf16_t*   Weff  = (bf16_t*)alloc(2048ull * 512 * 2);
  bf16_t*   linWb = (bf16_t*)alloc(64ull * 512 * 2);
  bf16_t*   Wx    = (bf16_t*)alloc(16ull * 8192 * 2);
  bf16_t*   xb    = (bf16_t*)alloc((size_t)N_TIN * N_B * N_D * 2);
  bf16_t*   hb0   = (bf16_t*)alloc((size_t)N_B * N_H * 2);
  bf16_t*   hb1   = (bf16_t*)alloc((size_t)N_B * N_H * 2);
  unsigned* leaf  = (unsigned*)alloc(1024);

  prep_weff<<<2048, 256, 0, stream>>>(dWih, dWhh, linW, Weff);
  prep_wx<<<16, 256, 0, stream>>>(eWih, Wx);
  cvt_bf16_v4<<<32, 256, 0, stream>>>(linW, linWb, 64 * 512 / 4);
  cvt_bf16_v4<<<2048, 256, 0, stream>>>(x_f, xb, N_TIN * N_B * N_D / 4);
  hipMemsetAsync(leaf, 0, 1024, stream);

  lstm_persist<<<dim3(256), dim3(512), 0, stream>>>(
      xb, Wx, eWhh, ebih, ebhh, dWih, dWhh, dbih, dbhh,
      linb, Weff, linWb, hb0, hb1, out, leaf);
}